// Round 18
// baseline (79.485 us; speedup 1.0000x reference)
//
#include <hip/hip_runtime.h>
#include <hip/hip_fp16.h>

#define W 144
#define PLANE (W * W)
#define VOL (W * W * W)
#define NB 2
#define WIN 11
#define PAD 5
#define YCH 24
#define YC (W / YCH)           // 6
#define NSTEPS (YC + 2 * PAD)  // 16
#define ZCH 6
#define ZCL (W / ZCH)          // 24
#define WPB 4
#define NXCD 8
#define NWAVES (NB * W * YCH)  // 6912
#define NZB (NB * W * ZCH)     // 1728

// DPP lane shift with old=0 (edge/exec-off lanes read 0).
template <int CTRL>
__device__ __forceinline__ float dpp0(float x) {
    return __int_as_float(
        __builtin_amdgcn_update_dpp(0, __float_as_int(x), CTRL, 0xf, 0xf, false));
}
#define SHR1(v) dpp0<0x138>(v)
#define SHL1(v) dpp0<0x130>(v)

// Lane l holds v at x = 4l-8 .. 4l-5. 11-tap x-window sums for its 4 positions
// using only wave shifts (verified on-chip R8/R12/R13/R14, absmax 0).
__device__ __forceinline__ float4 win11x4(const float4 v) {
    const float pre2 = v.x + v.y;
    const float pre3 = pre2 + v.z;
    const float q = pre3 + v.w;
    const float suf2 = v.z + v.w;
    const float suf3 = suf2 + v.y;
    const float qm1 = SHR1(q);
    const float sfx2m1 = SHR1(suf2);
    const float sfx3m1 = SHR1(suf3);
    const float sfx1m2 = SHR1(SHR1(v.w));
    const float qp1 = SHL1(q);
    const float pfx2p1 = SHL1(pre2);
    const float pfx3p1 = SHL1(pre3);
    const float pfx1p2 = SHL1(SHL1(v.x));
    float4 w;
    w.x = (sfx1m2 + qm1) + (q + pfx2p1);
    w.y = qm1 + (q + pfx3p1);
    w.z = sfx3m1 + (q + qp1);
    w.w = (sfx2m1 + q) + (qp1 + pfx1p2);
    return w;
}

__device__ __forceinline__ uint2 pack4h(float a, float b, float c, float d) {
    const __half2 lo = __floats2half2_rn(a, b);
    const __half2 hi = __floats2half2_rn(c, d);
    uint2 r;
    r.x = __builtin_bit_cast(unsigned int, lo);
    r.y = __builtin_bit_cast(unsigned int, hi);
    return r;
}

// kF: ringless fat-4 x+y pass, ROLLED 16-step loop, fp16 ws in [b][y][z][x]
// layout (z-contiguous planes per y) so k3's z-walk is stride-1152B streaming.
__global__ __launch_bounds__(WPB * 64) void
kF_xypass(const float* __restrict__ pred, const float* __restrict__ targ,
          uint2* __restrict__ wsh, double* __restrict__ slotW) {
    const int tid = threadIdx.x;
    const int l = tid & 63;
    const int wid = tid >> 6;

    // bijective XCD swizzle (nwg % 8 == 0)
    const int nwg = NWAVES / WPB;         // 1728
    const int q = nwg / NXCD;             // 216
    const int hw = (int)blockIdx.x;
    const int logical = (hw % NXCD) * q + hw / NXCD;

    int wg = logical * WPB + wid;
    const int yc = wg % YCH; wg /= YCH;
    const int z = wg % W; wg /= W;
    const int b = wg;
    const int y0 = yc * YC;

    const int xbase = 4 * l - 8;                 // lanes 2..37 own x 0..143
    const bool vx = (xbase >= 0) && (xbase < W);
    const float* __restrict__ gp = pred + (size_t)b * VOL + (size_t)z * PLANE + xbase;
    const float* __restrict__ gt = targ + (size_t)b * VOL + (size_t)z * PLANE + xbase;

    const float4 z4 = make_float4(0.f, 0.f, 0.f, 0.f);
    float l1 = 0.f;

    if (vx) {
        float4 s_p = z4, s_t = z4, s_pt = z4, s_sq = z4;
        float4 pa = z4, ta = z4, pn = z4, tn = z4, po = z4, to = z4;

        {
            const int g0 = y0 - PAD;
            if (g0 >= 0) {
                pa = *reinterpret_cast<const float4*>(gp + (size_t)g0 * W);
                ta = *reinterpret_cast<const float4*>(gt + (size_t)g0 * W);
            }
            const int g1 = y0 - PAD + 1;
            if (g1 >= 0) {
                pn = *reinterpret_cast<const float4*>(gp + (size_t)g1 * W);
                tn = *reinterpret_cast<const float4*>(gt + (size_t)g1 * W);
            }
        }

        // transposed ws: offset = b*VOL + y*PLANE + z*W + x; per output row += PLANE
        uint2* outp = wsh + (size_t)b * VOL + (size_t)y0 * PLANE + (size_t)z * W + xbase;

#pragma unroll 1
        for (int i = 0; i < NSTEPS; ++i) {
            const float4 p4 = pa, t4 = ta;
            pa = pn; ta = tn;
            {
                const int g = y0 - PAD + i + 2;
                if (i < NSTEPS - 2 && g >= 0 && g < W) {
                    pn = *reinterpret_cast<const float4*>(gp + (size_t)g * W);
                    tn = *reinterpret_cast<const float4*>(gt + (size_t)g * W);
                } else {
                    pn = z4; tn = z4;
                }
            }

            if (i >= PAD && i < PAD + YC) {  // core rows: L1 (uniform guard)
                l1 += (fabsf(p4.x - t4.x) + fabsf(p4.y - t4.y)) +
                      (fabsf(p4.z - t4.z) + fabsf(p4.w - t4.w));
            }

            // add new row
            s_p.x += p4.x; s_p.y += p4.y; s_p.z += p4.z; s_p.w += p4.w;
            s_t.x += t4.x; s_t.y += t4.y; s_t.z += t4.z; s_t.w += t4.w;
            s_pt.x += p4.x * t4.x; s_pt.y += p4.y * t4.y;
            s_pt.z += p4.z * t4.z; s_pt.w += p4.w * t4.w;
            s_sq.x += fmaf(p4.x, p4.x, t4.x * t4.x);
            s_sq.y += fmaf(p4.y, p4.y, t4.y * t4.y);
            s_sq.z += fmaf(p4.z, p4.z, t4.z * t4.z);
            s_sq.w += fmaf(p4.w, p4.w, t4.w * t4.w);

            if (i >= WIN) {  // subtract row (i-11), prefetched last step
                s_p.x -= po.x; s_p.y -= po.y; s_p.z -= po.z; s_p.w -= po.w;
                s_t.x -= to.x; s_t.y -= to.y; s_t.z -= to.z; s_t.w -= to.w;
                s_pt.x -= po.x * to.x; s_pt.y -= po.y * to.y;
                s_pt.z -= po.z * to.z; s_pt.w -= po.w * to.w;
                s_sq.x -= fmaf(po.x, po.x, to.x * to.x);
                s_sq.y -= fmaf(po.y, po.y, to.y * to.y);
                s_sq.z -= fmaf(po.z, po.z, to.z * to.z);
                s_sq.w -= fmaf(po.w, po.w, to.w * to.w);
            }

            if (i >= 2 * PAD) {  // output rows (uniform guard)
                if (i < NSTEPS - 1) {  // prefetch old row for step i+1
                    const int g = y0 + i - 15;  // (i+1) - 11 - PAD + y0
                    if (g >= 0) {
                        po = *reinterpret_cast<const float4*>(gp + (size_t)g * W);
                        to = *reinterpret_cast<const float4*>(gt + (size_t)g * W);
                    } else {
                        po = z4; to = z4;
                    }
                }
                const float4 w0 = win11x4(s_p);
                const float4 w1 = win11x4(s_t);
                const float4 w2 = win11x4(s_pt);
                const float4 w3 = win11x4(s_sq);
                const uint2 q0 = pack4h(w0.x, w1.x, w2.x, w3.x);
                const uint2 q1 = pack4h(w0.y, w1.y, w2.y, w3.y);
                const uint2 q2 = pack4h(w0.z, w1.z, w2.z, w3.z);
                const uint2 q3 = pack4h(w0.w, w1.w, w2.w, w3.w);
                uint4* o4 = reinterpret_cast<uint4*>(outp);
                o4[0] = make_uint4(q0.x, q0.y, q1.x, q1.y);
                o4[1] = make_uint4(q2.x, q2.y, q3.x, q3.y);
                outp += PLANE;
            }
        }
    }

    // wave-level reduction of l1 (pad lanes hold 0) -> unique slot
    l1 += __shfl_xor(l1, 32);
    l1 += __shfl_xor(l1, 16);
    l1 += __shfl_xor(l1, 8);
    l1 += __shfl_xor(l1, 4);
    l1 += __shfl_xor(l1, 2);
    l1 += __shfl_xor(l1, 1);
    if (l == 0) slotW[logical * WPB + wid] = (double)l1;
}

// K3: z-window ring over fp16 fields in [b][y][z][x] layout — stride-1152B
// streaming z-walk with 2-deep register prefetch. Block partial -> unique slot.
__global__ void k3_zpass(const uint2* __restrict__ wsh, double* __restrict__ slotS) {
    const int x = threadIdx.x;
    int bid = blockIdx.x;
    const int c = bid % ZCH; bid /= ZCH;
    const int y = bid % W; bid /= W;
    const int b = bid;
    const int zstart = c * ZCL;

    const uint2* F = wsh + (size_t)b * VOL + (size_t)y * PLANE + x;

    float r0[WIN], r1[WIN], r2[WIN], r3[WIN];
    float s0 = 0.f, s1 = 0.f, s2 = 0.f, s3 = 0.f;
#pragma unroll
    for (int k = 0; k < WIN; ++k) { r0[k] = 0.f; r1[k] = 0.f; r2[k] = 0.f; r3[k] = 0.f; }

    const float inv = 1.0f / 1331.0f;
    const float C1 = 0.01f * 0.01f;
    const float C2 = 0.03f * 0.03f;
    float ssim_acc = 0.f;

    const int NZ = ZCL + 2 * PAD;  // 34

    // bounds-checked unpack load
    auto loadz = [&](int i) -> float4 {
        const int zl = zstart - PAD + i;
        if (zl >= 0 && zl < W && i < NZ) {
            const uint2 uu = F[(size_t)zl * W];
            const float2 flo = __half22float2(__builtin_bit_cast(__half2, uu.x));
            const float2 fhi = __half22float2(__builtin_bit_cast(__half2, uu.y));
            return make_float4(flo.x, flo.y, fhi.x, fhi.y);
        }
        return make_float4(0.f, 0.f, 0.f, 0.f);
    };

    float4 va = loadz(0);
    float4 vb = loadz(1);

    for (int cc = 0; cc < 4; ++cc) {
#pragma unroll
        for (int u = 0; u < WIN; ++u) {
            const int i = cc * WIN + u;
            if (i < NZ) {
                const float4 v = va;
                va = vb;
                vb = loadz(i + 2);
                s0 += v.x - r0[u]; r0[u] = v.x;
                s1 += v.y - r1[u]; r1[u] = v.y;
                s2 += v.z - r2[u]; r2[u] = v.z;
                s3 += v.w - r3[u]; r3[u] = v.w;
                if (i >= 2 * PAD) {
                    const float mu_p = s0 * inv;
                    const float mu_t = s1 * inv;
                    const float ept = s2 * inv;
                    const float esq = s3 * inv;
                    const float mupt = mu_p * mu_t;
                    const float musq = mu_p * mu_p + mu_t * mu_t;
                    const float sig_pt = ept - mupt;
                    const float sigsum = esq - musq;
                    const float num = (2.f * mupt + C1) * (2.f * sig_pt + C2);
                    const float den = (musq + C1) * (sigsum + C2);
                    ssim_acc += num / den;
                }
            }
        }
    }

    __shared__ float red[W];
    red[x] = ssim_acc;
    __syncthreads();
    if (x < 16) {
        float s2r = 0.f;
#pragma unroll
        for (int k = 0; k < 9; ++k) s2r += red[x + 16 * k];
        s2r += __shfl_down(s2r, 8);
        s2r += __shfl_down(s2r, 4);
        s2r += __shfl_down(s2r, 2);
        s2r += __shfl_down(s2r, 1);
        if (x == 0) slotS[blockIdx.x] = (double)s2r;
    }
}

// K4: reduce the 6912 + 1728 slots, write the 3 outputs. Deterministic order.
__global__ void k4_final(const double* __restrict__ slotW,
                         const double* __restrict__ slotS, float* __restrict__ out) {
    const int x = threadIdx.x;
    double a = 0.0, s = 0.0;
    for (int i = x; i < NWAVES; i += 256) a += slotW[i];
    for (int i = x; i < NZB; i += 256) s += slotS[i];
    __shared__ double d1[256];
    __shared__ double d2[256];
    d1[x] = a; d2[x] = s;
    __syncthreads();
    for (int st = 128; st > 0; st >>= 1) {
        if (x < st) { d1[x] += d1[x + st]; d2[x] += d2[x + st]; }
        __syncthreads();
    }
    if (x == 0) {
        const double n = (double)NB * (double)VOL;
        const double l1 = d1[0] / n;
        const double ssim_loss = 1.0 - d2[0] / n;
        out[0] = (float)(l1 + 0.5 * ssim_loss);
        out[1] = (float)l1;
        out[2] = (float)ssim_loss;
    }
}

extern "C" void kernel_launch(void* const* d_in, const int* in_sizes, int n_in,
                              void* d_out, int out_size, void* d_ws, size_t ws_size,
                              hipStream_t stream) {
    const float* pred = (const float*)d_in[0];
    const float* targ = (const float*)d_in[1];
    float* out = (float*)d_out;
    uint2* wsh = (uint2*)d_ws;                                  // half4 per voxel, 47.8 MB
    double* slotW = (double*)((char*)d_ws + (size_t)NB * VOL * sizeof(uint2));
    double* slotS = slotW + NWAVES;

    const int nwg = NWAVES / WPB;  // 1728 blocks
    kF_xypass<<<nwg, WPB * 64, 0, stream>>>(pred, targ, wsh, slotW);
    k3_zpass<<<NZB, W, 0, stream>>>(wsh, slotS);
    k4_final<<<1, 256, 0, stream>>>(slotW, slotS, out);
}

// Round 19
// 71.770 us; speedup vs baseline: 1.1075x; 1.1075x over previous
//
#include <hip/hip_runtime.h>
#include <hip/hip_fp16.h>

#define W 144
#define PLANE (W * W)
#define VOL (W * W * W)
#define NB 2
#define WIN 11
#define PAD 5
#define YCH 24
#define YC (W / YCH)           // 6
#define NSTEPS (YC + 2 * PAD)  // 16
#define ZCH 6
#define ZCL (W / ZCH)          // 24
#define WPB 4
#define NXCD 8
#define NWAVES (NB * W * YCH)        // 6912
#define NZB (NB * (W / 2) * ZCH)     // 864

// DPP lane shift with old=0 (edge/exec-off lanes read 0).
template <int CTRL>
__device__ __forceinline__ float dpp0(float x) {
    return __int_as_float(
        __builtin_amdgcn_update_dpp(0, __float_as_int(x), CTRL, 0xf, 0xf, false));
}
#define SHR1(v) dpp0<0x138>(v)
#define SHL1(v) dpp0<0x130>(v)

// Lane l holds v at x = 4l-8 .. 4l-5. 11-tap x-window sums for its 4 positions
// using only wave shifts (verified on-chip R8/R12/R13/R14, absmax 0).
__device__ __forceinline__ float4 win11x4(const float4 v) {
    const float pre2 = v.x + v.y;
    const float pre3 = pre2 + v.z;
    const float q = pre3 + v.w;
    const float suf2 = v.z + v.w;
    const float suf3 = suf2 + v.y;
    const float qm1 = SHR1(q);
    const float sfx2m1 = SHR1(suf2);
    const float sfx3m1 = SHR1(suf3);
    const float sfx1m2 = SHR1(SHR1(v.w));
    const float qp1 = SHL1(q);
    const float pfx2p1 = SHL1(pre2);
    const float pfx3p1 = SHL1(pre3);
    const float pfx1p2 = SHL1(SHL1(v.x));
    float4 w;
    w.x = (sfx1m2 + qm1) + (q + pfx2p1);
    w.y = qm1 + (q + pfx3p1);
    w.z = sfx3m1 + (q + qp1);
    w.w = (sfx2m1 + q) + (qp1 + pfx1p2);
    return w;
}

__device__ __forceinline__ uint2 pack4h(float a, float b, float c, float d) {
    const __half2 lo = __floats2half2_rn(a, b);
    const __half2 hi = __floats2half2_rn(c, d);
    uint2 r;
    r.x = __builtin_bit_cast(unsigned int, lo);
    r.y = __builtin_bit_cast(unsigned int, hi);
    return r;
}

__device__ __forceinline__ float4 unpack4h(unsigned int lo, unsigned int hi) {
    const float2 flo = __half22float2(__builtin_bit_cast(__half2, lo));
    const float2 fhi = __half22float2(__builtin_bit_cast(__half2, hi));
    return make_float4(flo.x, flo.y, fhi.x, fhi.y);
}

// kF: ringless fat-4 x+y pass, ROLLED 16-step loop, fp16 ws in [b][y][z][x]
// layout. IDENTICAL to R18 (measured <=44us, est ~28-32).
__global__ __launch_bounds__(WPB * 64) void
kF_xypass(const float* __restrict__ pred, const float* __restrict__ targ,
          uint2* __restrict__ wsh, double* __restrict__ slotW) {
    const int tid = threadIdx.x;
    const int l = tid & 63;
    const int wid = tid >> 6;

    // bijective XCD swizzle (nwg % 8 == 0)
    const int nwg = NWAVES / WPB;         // 1728
    const int q = nwg / NXCD;             // 216
    const int hw = (int)blockIdx.x;
    const int logical = (hw % NXCD) * q + hw / NXCD;

    int wg = logical * WPB + wid;
    const int yc = wg % YCH; wg /= YCH;
    const int z = wg % W; wg /= W;
    const int b = wg;
    const int y0 = yc * YC;

    const int xbase = 4 * l - 8;                 // lanes 2..37 own x 0..143
    const bool vx = (xbase >= 0) && (xbase < W);
    const float* __restrict__ gp = pred + (size_t)b * VOL + (size_t)z * PLANE + xbase;
    const float* __restrict__ gt = targ + (size_t)b * VOL + (size_t)z * PLANE + xbase;

    const float4 z4 = make_float4(0.f, 0.f, 0.f, 0.f);
    float l1 = 0.f;

    if (vx) {
        float4 s_p = z4, s_t = z4, s_pt = z4, s_sq = z4;
        float4 pa = z4, ta = z4, pn = z4, tn = z4, po = z4, to = z4;

        {
            const int g0 = y0 - PAD;
            if (g0 >= 0) {
                pa = *reinterpret_cast<const float4*>(gp + (size_t)g0 * W);
                ta = *reinterpret_cast<const float4*>(gt + (size_t)g0 * W);
            }
            const int g1 = y0 - PAD + 1;
            if (g1 >= 0) {
                pn = *reinterpret_cast<const float4*>(gp + (size_t)g1 * W);
                tn = *reinterpret_cast<const float4*>(gt + (size_t)g1 * W);
            }
        }

        uint2* outp = wsh + (size_t)b * VOL + (size_t)y0 * PLANE + (size_t)z * W + xbase;

#pragma unroll 1
        for (int i = 0; i < NSTEPS; ++i) {
            const float4 p4 = pa, t4 = ta;
            pa = pn; ta = tn;
            {
                const int g = y0 - PAD + i + 2;
                if (i < NSTEPS - 2 && g >= 0 && g < W) {
                    pn = *reinterpret_cast<const float4*>(gp + (size_t)g * W);
                    tn = *reinterpret_cast<const float4*>(gt + (size_t)g * W);
                } else {
                    pn = z4; tn = z4;
                }
            }

            if (i >= PAD && i < PAD + YC) {
                l1 += (fabsf(p4.x - t4.x) + fabsf(p4.y - t4.y)) +
                      (fabsf(p4.z - t4.z) + fabsf(p4.w - t4.w));
            }

            s_p.x += p4.x; s_p.y += p4.y; s_p.z += p4.z; s_p.w += p4.w;
            s_t.x += t4.x; s_t.y += t4.y; s_t.z += t4.z; s_t.w += t4.w;
            s_pt.x += p4.x * t4.x; s_pt.y += p4.y * t4.y;
            s_pt.z += p4.z * t4.z; s_pt.w += p4.w * t4.w;
            s_sq.x += fmaf(p4.x, p4.x, t4.x * t4.x);
            s_sq.y += fmaf(p4.y, p4.y, t4.y * t4.y);
            s_sq.z += fmaf(p4.z, p4.z, t4.z * t4.z);
            s_sq.w += fmaf(p4.w, p4.w, t4.w * t4.w);

            if (i >= WIN) {
                s_p.x -= po.x; s_p.y -= po.y; s_p.z -= po.z; s_p.w -= po.w;
                s_t.x -= to.x; s_t.y -= to.y; s_t.z -= to.z; s_t.w -= to.w;
                s_pt.x -= po.x * to.x; s_pt.y -= po.y * to.y;
                s_pt.z -= po.z * to.z; s_pt.w -= po.w * to.w;
                s_sq.x -= fmaf(po.x, po.x, to.x * to.x);
                s_sq.y -= fmaf(po.y, po.y, to.y * to.y);
                s_sq.z -= fmaf(po.z, po.z, to.z * to.z);
                s_sq.w -= fmaf(po.w, po.w, to.w * to.w);
            }

            if (i >= 2 * PAD) {
                if (i < NSTEPS - 1) {
                    const int g = y0 + i - 15;
                    if (g >= 0) {
                        po = *reinterpret_cast<const float4*>(gp + (size_t)g * W);
                        to = *reinterpret_cast<const float4*>(gt + (size_t)g * W);
                    } else {
                        po = z4; to = z4;
                    }
                }
                const float4 w0 = win11x4(s_p);
                const float4 w1 = win11x4(s_t);
                const float4 w2 = win11x4(s_pt);
                const float4 w3 = win11x4(s_sq);
                const uint2 q0 = pack4h(w0.x, w1.x, w2.x, w3.x);
                const uint2 q1 = pack4h(w0.y, w1.y, w2.y, w3.y);
                const uint2 q2 = pack4h(w0.z, w1.z, w2.z, w3.z);
                const uint2 q3 = pack4h(w0.w, w1.w, w2.w, w3.w);
                uint4* o4 = reinterpret_cast<uint4*>(outp);
                o4[0] = make_uint4(q0.x, q0.y, q1.x, q1.y);
                o4[1] = make_uint4(q2.x, q2.y, q3.x, q3.y);
                outp += PLANE;
            }
        }
    }

    l1 += __shfl_xor(l1, 32);
    l1 += __shfl_xor(l1, 16);
    l1 += __shfl_xor(l1, 8);
    l1 += __shfl_xor(l1, 4);
    l1 += __shfl_xor(l1, 2);
    l1 += __shfl_xor(l1, 1);
    if (l == 0) slotW[logical * WPB + wid] = (double)l1;
}

// K3: wide-load ringless z-pass. Block = (b, y-pair, z-chunk), 144 threads;
// thread t -> row y = 2*yp + t/72, voxel pair x = 2*(t%72). One uint4 (16B)
// load per step covers both voxels; z-window via running sum + re-loaded
// (z-11) subtraction (cache-hot, bit-identical). Small rolled body, direct
// guarded loads (the R11-measured-fast structure).
__global__ void k3_zpass(const uint2* __restrict__ wsh, double* __restrict__ slotS) {
    const int t = threadIdx.x;
    int bid = blockIdx.x;
    const int c = bid % ZCH; bid /= ZCH;
    const int yp = bid % (W / 2); bid /= (W / 2);
    const int b = bid;
    const int y = 2 * yp + (t / 72);
    const int xp = t % 72;
    const int zstart = c * ZCL;

    const uint2* F = wsh + (size_t)b * VOL + (size_t)y * PLANE + 2 * xp;

    float a0 = 0.f, a1 = 0.f, a2 = 0.f, a3 = 0.f;   // voxel A sums
    float b0 = 0.f, b1 = 0.f, b2 = 0.f, b3 = 0.f;   // voxel B sums
    const float inv = 1.0f / 1331.0f;
    const float C1 = 0.01f * 0.01f;
    const float C2 = 0.03f * 0.03f;
    float ssim_acc = 0.f;

    const int NZ = ZCL + 2 * PAD;  // 34
#pragma unroll 1
    for (int i = 0; i < NZ; ++i) {
        const int zl = zstart - PAD + i;
        if (zl >= 0 && zl < W) {  // add new z-row (uniform guard)
            const uint4 uu = *reinterpret_cast<const uint4*>(F + (size_t)zl * W);
            const float4 vA = unpack4h(uu.x, uu.y);
            const float4 vB = unpack4h(uu.z, uu.w);
            a0 += vA.x; a1 += vA.y; a2 += vA.z; a3 += vA.w;
            b0 += vB.x; b1 += vB.y; b2 += vB.z; b3 += vB.w;
        }
        const int zo = zl - WIN;
        if (i >= WIN && zo >= 0) {  // subtract z-row added 11 steps ago (cache-hot)
            const uint4 uu = *reinterpret_cast<const uint4*>(F + (size_t)zo * W);
            const float4 vA = unpack4h(uu.x, uu.y);
            const float4 vB = unpack4h(uu.z, uu.w);
            a0 -= vA.x; a1 -= vA.y; a2 -= vA.z; a3 -= vA.w;
            b0 -= vB.x; b1 -= vB.y; b2 -= vB.z; b3 -= vB.w;
        }
        if (i >= 2 * PAD) {  // SSIM for both voxels
            {
                const float mu_p = a0 * inv, mu_t = a1 * inv;
                const float ept = a2 * inv, esq = a3 * inv;
                const float mupt = mu_p * mu_t;
                const float musq = mu_p * mu_p + mu_t * mu_t;
                const float num = (2.f * mupt + C1) * (2.f * (ept - mupt) + C2);
                const float den = (musq + C1) * ((esq - musq) + C2);
                ssim_acc += num / den;
            }
            {
                const float mu_p = b0 * inv, mu_t = b1 * inv;
                const float ept = b2 * inv, esq = b3 * inv;
                const float mupt = mu_p * mu_t;
                const float musq = mu_p * mu_p + mu_t * mu_t;
                const float num = (2.f * mupt + C1) * (2.f * (ept - mupt) + C2);
                const float den = (musq + C1) * ((esq - musq) + C2);
                ssim_acc += num / den;
            }
        }
    }

    __shared__ float red[W];
    red[t] = ssim_acc;
    __syncthreads();
    if (t < 16) {
        float s2r = 0.f;
#pragma unroll
        for (int k = 0; k < 9; ++k) s2r += red[t + 16 * k];
        s2r += __shfl_down(s2r, 8);
        s2r += __shfl_down(s2r, 4);
        s2r += __shfl_down(s2r, 2);
        s2r += __shfl_down(s2r, 1);
        if (t == 0) slotS[blockIdx.x] = (double)s2r;
    }
}

// K4: reduce the 6912 + 864 slots, write the 3 outputs. Deterministic order.
__global__ void k4_final(const double* __restrict__ slotW,
                         const double* __restrict__ slotS, float* __restrict__ out) {
    const int x = threadIdx.x;
    double a = 0.0, s = 0.0;
    for (int i = x; i < NWAVES; i += 256) a += slotW[i];
    for (int i = x; i < NZB; i += 256) s += slotS[i];
    __shared__ double d1[256];
    __shared__ double d2[256];
    d1[x] = a; d2[x] = s;
    __syncthreads();
    for (int st = 128; st > 0; st >>= 1) {
        if (x < st) { d1[x] += d1[x + st]; d2[x] += d2[x + st]; }
        __syncthreads();
    }
    if (x == 0) {
        const double n = (double)NB * (double)VOL;
        const double l1 = d1[0] / n;
        const double ssim_loss = 1.0 - d2[0] / n;
        out[0] = (float)(l1 + 0.5 * ssim_loss);
        out[1] = (float)l1;
        out[2] = (float)ssim_loss;
    }
}

extern "C" void kernel_launch(void* const* d_in, const int* in_sizes, int n_in,
                              void* d_out, int out_size, void* d_ws, size_t ws_size,
                              hipStream_t stream) {
    const float* pred = (const float*)d_in[0];
    const float* targ = (const float*)d_in[1];
    float* out = (float*)d_out;
    uint2* wsh = (uint2*)d_ws;                                  // half4 per voxel, 47.8 MB
    double* slotW = (double*)((char*)d_ws + (size_t)NB * VOL * sizeof(uint2));
    double* slotS = slotW + NWAVES;

    const int nwg = NWAVES / WPB;  // 1728 blocks
    kF_xypass<<<nwg, WPB * 64, 0, stream>>>(pred, targ, wsh, slotW);
    k3_zpass<<<NZB, W, 0, stream>>>(wsh, slotS);
    k4_final<<<1, 256, 0, stream>>>(slotW, slotS, out);
}

// Round 20
// 67.503 us; speedup vs baseline: 1.1775x; 1.0632x over previous
//
#include <hip/hip_runtime.h>
#include <hip/hip_fp16.h>

#define W 144
#define PLANE (W * W)
#define VOL (W * W * W)
#define NB 2
#define WIN 11
#define PAD 5
#define YCH 12
#define YC (W / YCH)           // 12
#define NSTEPS (YC + 2 * PAD)  // 22
#define ZCH 6
#define ZCL (W / ZCH)          // 24
#define WPB 4
#define NXCD 8
#define NWAVES (NB * W * YCH)        // 3456
#define NZB (NB * (W / 2) * ZCH)     // 864

// DPP lane shift with old=0 (edge/exec-off lanes read 0).
template <int CTRL>
__device__ __forceinline__ float dpp0(float x) {
    return __int_as_float(
        __builtin_amdgcn_update_dpp(0, __float_as_int(x), CTRL, 0xf, 0xf, false));
}
#define SHR1(v) dpp0<0x138>(v)
#define SHL1(v) dpp0<0x130>(v)

// Lane l holds v at x = 4l-8 .. 4l-5. 11-tap x-window sums for its 4 positions
// using only wave shifts (verified on-chip R8/R12/R13/R14, absmax 0).
__device__ __forceinline__ float4 win11x4(const float4 v) {
    const float pre2 = v.x + v.y;
    const float pre3 = pre2 + v.z;
    const float q = pre3 + v.w;
    const float suf2 = v.z + v.w;
    const float suf3 = suf2 + v.y;
    const float qm1 = SHR1(q);
    const float sfx2m1 = SHR1(suf2);
    const float sfx3m1 = SHR1(suf3);
    const float sfx1m2 = SHR1(SHR1(v.w));
    const float qp1 = SHL1(q);
    const float pfx2p1 = SHL1(pre2);
    const float pfx3p1 = SHL1(pre3);
    const float pfx1p2 = SHL1(SHL1(v.x));
    float4 w;
    w.x = (sfx1m2 + qm1) + (q + pfx2p1);
    w.y = qm1 + (q + pfx3p1);
    w.z = sfx3m1 + (q + qp1);
    w.w = (sfx2m1 + q) + (qp1 + pfx1p2);
    return w;
}

__device__ __forceinline__ uint2 pack4h(float a, float b, float c, float d) {
    const __half2 lo = __floats2half2_rn(a, b);
    const __half2 hi = __floats2half2_rn(c, d);
    uint2 r;
    r.x = __builtin_bit_cast(unsigned int, lo);
    r.y = __builtin_bit_cast(unsigned int, hi);
    return r;
}

__device__ __forceinline__ float4 unpack4h(unsigned int lo, unsigned int hi) {
    const float2 flo = __half22float2(__builtin_bit_cast(__half2, lo));
    const float2 fhi = __half22float2(__builtin_bit_cast(__half2, hi));
    return make_float4(flo.x, flo.y, fhi.x, fhi.y);
}

// kF: ringless fat-4 x+y pass, ROLLED 22-step loop, fp16 ws in [b][y][z][x]
// layout. YC=12: 1.83 steps / 2.75 row-loads per output row (vs 2.67 / 3.5).
__global__ __launch_bounds__(WPB * 64) void
kF_xypass(const float* __restrict__ pred, const float* __restrict__ targ,
          uint2* __restrict__ wsh, double* __restrict__ slotW) {
    const int tid = threadIdx.x;
    const int l = tid & 63;
    const int wid = tid >> 6;

    // bijective XCD swizzle (nwg % 8 == 0)
    const int nwg = NWAVES / WPB;         // 864
    const int q = nwg / NXCD;             // 108
    const int hw = (int)blockIdx.x;
    const int logical = (hw % NXCD) * q + hw / NXCD;

    int wg = logical * WPB + wid;
    const int yc = wg % YCH; wg /= YCH;
    const int z = wg % W; wg /= W;
    const int b = wg;
    const int y0 = yc * YC;

    const int xbase = 4 * l - 8;                 // lanes 2..37 own x 0..143
    const bool vx = (xbase >= 0) && (xbase < W);
    const float* __restrict__ gp = pred + (size_t)b * VOL + (size_t)z * PLANE + xbase;
    const float* __restrict__ gt = targ + (size_t)b * VOL + (size_t)z * PLANE + xbase;

    const float4 z4 = make_float4(0.f, 0.f, 0.f, 0.f);
    float l1 = 0.f;

    if (vx) {
        float4 s_p = z4, s_t = z4, s_pt = z4, s_sq = z4;
        float4 pa = z4, ta = z4, pn = z4, tn = z4, po = z4, to = z4;

        {
            const int g0 = y0 - PAD;
            if (g0 >= 0) {
                pa = *reinterpret_cast<const float4*>(gp + (size_t)g0 * W);
                ta = *reinterpret_cast<const float4*>(gt + (size_t)g0 * W);
            }
            const int g1 = y0 - PAD + 1;
            if (g1 >= 0) {
                pn = *reinterpret_cast<const float4*>(gp + (size_t)g1 * W);
                tn = *reinterpret_cast<const float4*>(gt + (size_t)g1 * W);
            }
        }

        uint2* outp = wsh + (size_t)b * VOL + (size_t)y0 * PLANE + (size_t)z * W + xbase;

#pragma unroll 1
        for (int i = 0; i < NSTEPS; ++i) {
            const float4 p4 = pa, t4 = ta;
            pa = pn; ta = tn;
            {
                const int g = y0 - PAD + i + 2;
                if (i < NSTEPS - 2 && g >= 0 && g < W) {
                    pn = *reinterpret_cast<const float4*>(gp + (size_t)g * W);
                    tn = *reinterpret_cast<const float4*>(gt + (size_t)g * W);
                } else {
                    pn = z4; tn = z4;
                }
            }

            if (i >= PAD && i < PAD + YC) {
                l1 += (fabsf(p4.x - t4.x) + fabsf(p4.y - t4.y)) +
                      (fabsf(p4.z - t4.z) + fabsf(p4.w - t4.w));
            }

            s_p.x += p4.x; s_p.y += p4.y; s_p.z += p4.z; s_p.w += p4.w;
            s_t.x += t4.x; s_t.y += t4.y; s_t.z += t4.z; s_t.w += t4.w;
            s_pt.x += p4.x * t4.x; s_pt.y += p4.y * t4.y;
            s_pt.z += p4.z * t4.z; s_pt.w += p4.w * t4.w;
            s_sq.x += fmaf(p4.x, p4.x, t4.x * t4.x);
            s_sq.y += fmaf(p4.y, p4.y, t4.y * t4.y);
            s_sq.z += fmaf(p4.z, p4.z, t4.z * t4.z);
            s_sq.w += fmaf(p4.w, p4.w, t4.w * t4.w);

            if (i >= WIN) {
                s_p.x -= po.x; s_p.y -= po.y; s_p.z -= po.z; s_p.w -= po.w;
                s_t.x -= to.x; s_t.y -= to.y; s_t.z -= to.z; s_t.w -= to.w;
                s_pt.x -= po.x * to.x; s_pt.y -= po.y * to.y;
                s_pt.z -= po.z * to.z; s_pt.w -= po.w * to.w;
                s_sq.x -= fmaf(po.x, po.x, to.x * to.x);
                s_sq.y -= fmaf(po.y, po.y, to.y * to.y);
                s_sq.z -= fmaf(po.z, po.z, to.z * to.z);
                s_sq.w -= fmaf(po.w, po.w, to.w * to.w);
            }

            if (i >= 2 * PAD) {
                if (i < NSTEPS - 1) {  // prefetch old row for step i+1's subtract
                    const int g = y0 + i - 15;  // (i+1) - 11 - PAD + y0
                    if (g >= 0) {
                        po = *reinterpret_cast<const float4*>(gp + (size_t)g * W);
                        to = *reinterpret_cast<const float4*>(gt + (size_t)g * W);
                    } else {
                        po = z4; to = z4;
                    }
                }
                const float4 w0 = win11x4(s_p);
                const float4 w1 = win11x4(s_t);
                const float4 w2 = win11x4(s_pt);
                const float4 w3 = win11x4(s_sq);
                const uint2 q0 = pack4h(w0.x, w1.x, w2.x, w3.x);
                const uint2 q1 = pack4h(w0.y, w1.y, w2.y, w3.y);
                const uint2 q2 = pack4h(w0.z, w1.z, w2.z, w3.z);
                const uint2 q3 = pack4h(w0.w, w1.w, w2.w, w3.w);
                uint4* o4 = reinterpret_cast<uint4*>(outp);
                o4[0] = make_uint4(q0.x, q0.y, q1.x, q1.y);
                o4[1] = make_uint4(q2.x, q2.y, q3.x, q3.y);
                outp += PLANE;
            }
        }
    }

    l1 += __shfl_xor(l1, 32);
    l1 += __shfl_xor(l1, 16);
    l1 += __shfl_xor(l1, 8);
    l1 += __shfl_xor(l1, 4);
    l1 += __shfl_xor(l1, 2);
    l1 += __shfl_xor(l1, 1);
    if (l == 0) slotW[logical * WPB + wid] = (double)l1;
}

// K3: wide-load ringless z-pass (verified R19). Block = (b, y-pair, z-chunk),
// 144 threads; thread t -> row y = 2*yp + t/72, voxel pair x = 2*(t%72).
__global__ void k3_zpass(const uint2* __restrict__ wsh, double* __restrict__ slotS) {
    const int t = threadIdx.x;
    int bid = blockIdx.x;
    const int c = bid % ZCH; bid /= ZCH;
    const int yp = bid % (W / 2); bid /= (W / 2);
    const int b = bid;
    const int y = 2 * yp + (t / 72);
    const int xp = t % 72;
    const int zstart = c * ZCL;

    const uint2* F = wsh + (size_t)b * VOL + (size_t)y * PLANE + 2 * xp;

    float a0 = 0.f, a1 = 0.f, a2 = 0.f, a3 = 0.f;
    float b0 = 0.f, b1 = 0.f, b2 = 0.f, b3 = 0.f;
    const float inv = 1.0f / 1331.0f;
    const float C1 = 0.01f * 0.01f;
    const float C2 = 0.03f * 0.03f;
    float ssim_acc = 0.f;

    const int NZ = ZCL + 2 * PAD;  // 34
#pragma unroll 1
    for (int i = 0; i < NZ; ++i) {
        const int zl = zstart - PAD + i;
        if (zl >= 0 && zl < W) {
            const uint4 uu = *reinterpret_cast<const uint4*>(F + (size_t)zl * W);
            const float4 vA = unpack4h(uu.x, uu.y);
            const float4 vB = unpack4h(uu.z, uu.w);
            a0 += vA.x; a1 += vA.y; a2 += vA.z; a3 += vA.w;
            b0 += vB.x; b1 += vB.y; b2 += vB.z; b3 += vB.w;
        }
        const int zo = zl - WIN;
        if (i >= WIN && zo >= 0) {
            const uint4 uu = *reinterpret_cast<const uint4*>(F + (size_t)zo * W);
            const float4 vA = unpack4h(uu.x, uu.y);
            const float4 vB = unpack4h(uu.z, uu.w);
            a0 -= vA.x; a1 -= vA.y; a2 -= vA.z; a3 -= vA.w;
            b0 -= vB.x; b1 -= vB.y; b2 -= vB.z; b3 -= vB.w;
        }
        if (i >= 2 * PAD) {
            {
                const float mu_p = a0 * inv, mu_t = a1 * inv;
                const float ept = a2 * inv, esq = a3 * inv;
                const float mupt = mu_p * mu_t;
                const float musq = mu_p * mu_p + mu_t * mu_t;
                const float num = (2.f * mupt + C1) * (2.f * (ept - mupt) + C2);
                const float den = (musq + C1) * ((esq - musq) + C2);
                ssim_acc += num / den;
            }
            {
                const float mu_p = b0 * inv, mu_t = b1 * inv;
                const float ept = b2 * inv, esq = b3 * inv;
                const float mupt = mu_p * mu_t;
                const float musq = mu_p * mu_p + mu_t * mu_t;
                const float num = (2.f * mupt + C1) * (2.f * (ept - mupt) + C2);
                const float den = (musq + C1) * ((esq - musq) + C2);
                ssim_acc += num / den;
            }
        }
    }

    __shared__ float red[W];
    red[t] = ssim_acc;
    __syncthreads();
    if (t < 16) {
        float s2r = 0.f;
#pragma unroll
        for (int k = 0; k < 9; ++k) s2r += red[t + 16 * k];
        s2r += __shfl_down(s2r, 8);
        s2r += __shfl_down(s2r, 4);
        s2r += __shfl_down(s2r, 2);
        s2r += __shfl_down(s2r, 1);
        if (t == 0) slotS[blockIdx.x] = (double)s2r;
    }
}

// K4: reduce the 3456 + 864 slots, write the 3 outputs. Deterministic order.
__global__ void k4_final(const double* __restrict__ slotW,
                         const double* __restrict__ slotS, float* __restrict__ out) {
    const int x = threadIdx.x;
    double a = 0.0, s = 0.0;
    for (int i = x; i < NWAVES; i += 256) a += slotW[i];
    for (int i = x; i < NZB; i += 256) s += slotS[i];
    __shared__ double d1[256];
    __shared__ double d2[256];
    d1[x] = a; d2[x] = s;
    __syncthreads();
    for (int st = 128; st > 0; st >>= 1) {
        if (x < st) { d1[x] += d1[x + st]; d2[x] += d2[x + st]; }
        __syncthreads();
    }
    if (x == 0) {
        const double n = (double)NB * (double)VOL;
        const double l1 = d1[0] / n;
        const double ssim_loss = 1.0 - d2[0] / n;
        out[0] = (float)(l1 + 0.5 * ssim_loss);
        out[1] = (float)l1;
        out[2] = (float)ssim_loss;
    }
}

extern "C" void kernel_launch(void* const* d_in, const int* in_sizes, int n_in,
                              void* d_out, int out_size, void* d_ws, size_t ws_size,
                              hipStream_t stream) {
    const float* pred = (const float*)d_in[0];
    const float* targ = (const float*)d_in[1];
    float* out = (float*)d_out;
    uint2* wsh = (uint2*)d_ws;                                  // half4 per voxel, 47.8 MB
    double* slotW = (double*)((char*)d_ws + (size_t)NB * VOL * sizeof(uint2));
    double* slotS = slotW + NWAVES;

    const int nwg = NWAVES / WPB;  // 864 blocks
    kF_xypass<<<nwg, WPB * 64, 0, stream>>>(pred, targ, wsh, slotW);
    k3_zpass<<<NZB, W, 0, stream>>>(wsh, slotS);
    k4_final<<<1, 256, 0, stream>>>(slotW, slotS, out);
}

// Round 21
// 61.815 us; speedup vs baseline: 1.2859x; 1.0920x over previous
//
#include <hip/hip_runtime.h>
#include <hip/hip_fp16.h>

#define W 144
#define PLANE (W * W)
#define VOL (W * W * W)
#define NB 2
#define WIN 11
#define PAD 5
#define YCH 9
#define YC (W / YCH)           // 16
#define NSTEPS (YC + 2 * PAD)  // 26
#define ZCH 12
#define ZCL (W / ZCH)          // 12
#define WPB 4
#define NXCD 8
#define NWAVES (NB * W * YCH)        // 2592
#define NZB (NB * (W / 2) * ZCH)     // 1728

// DPP lane shift with old=0 (edge/exec-off lanes read 0).
template <int CTRL>
__device__ __forceinline__ float dpp0(float x) {
    return __int_as_float(
        __builtin_amdgcn_update_dpp(0, __float_as_int(x), CTRL, 0xf, 0xf, false));
}
#define SHR1(v) dpp0<0x138>(v)
#define SHL1(v) dpp0<0x130>(v)

// Lane l holds v at x = 4l-8 .. 4l-5. 11-tap x-window sums for its 4 positions
// using only wave shifts (verified on-chip R8/R12/R13/R14, absmax 0).
__device__ __forceinline__ float4 win11x4(const float4 v) {
    const float pre2 = v.x + v.y;
    const float pre3 = pre2 + v.z;
    const float q = pre3 + v.w;
    const float suf2 = v.z + v.w;
    const float suf3 = suf2 + v.y;
    const float qm1 = SHR1(q);
    const float sfx2m1 = SHR1(suf2);
    const float sfx3m1 = SHR1(suf3);
    const float sfx1m2 = SHR1(SHR1(v.w));
    const float qp1 = SHL1(q);
    const float pfx2p1 = SHL1(pre2);
    const float pfx3p1 = SHL1(pre3);
    const float pfx1p2 = SHL1(SHL1(v.x));
    float4 w;
    w.x = (sfx1m2 + qm1) + (q + pfx2p1);
    w.y = qm1 + (q + pfx3p1);
    w.z = sfx3m1 + (q + qp1);
    w.w = (sfx2m1 + q) + (qp1 + pfx1p2);
    return w;
}

__device__ __forceinline__ uint2 pack4h(float a, float b, float c, float d) {
    const __half2 lo = __floats2half2_rn(a, b);
    const __half2 hi = __floats2half2_rn(c, d);
    uint2 r;
    r.x = __builtin_bit_cast(unsigned int, lo);
    r.y = __builtin_bit_cast(unsigned int, hi);
    return r;
}

__device__ __forceinline__ float4 unpack4h(unsigned int lo, unsigned int hi) {
    const float2 flo = __half22float2(__builtin_bit_cast(__half2, lo));
    const float2 fhi = __half22float2(__builtin_bit_cast(__half2, hi));
    return make_float4(flo.x, flo.y, fhi.x, fhi.y);
}

// kF: ringless fat-4 x+y pass, ROLLED 26-step loop, fp16 ws in [b][y][z][x]
// layout. YC=16: 1.625 steps / 2.44 row-loads per output row.
__global__ __launch_bounds__(WPB * 64) void
kF_xypass(const float* __restrict__ pred, const float* __restrict__ targ,
          uint2* __restrict__ wsh, double* __restrict__ slotW) {
    const int tid = threadIdx.x;
    const int l = tid & 63;
    const int wid = tid >> 6;

    // bijective XCD swizzle (nwg % 8 == 0)
    const int nwg = NWAVES / WPB;         // 648
    const int q = nwg / NXCD;             // 81
    const int hw = (int)blockIdx.x;
    const int logical = (hw % NXCD) * q + hw / NXCD;

    int wg = logical * WPB + wid;
    const int yc = wg % YCH; wg /= YCH;
    const int z = wg % W; wg /= W;
    const int b = wg;
    const int y0 = yc * YC;

    const int xbase = 4 * l - 8;                 // lanes 2..37 own x 0..143
    const bool vx = (xbase >= 0) && (xbase < W);
    const float* __restrict__ gp = pred + (size_t)b * VOL + (size_t)z * PLANE + xbase;
    const float* __restrict__ gt = targ + (size_t)b * VOL + (size_t)z * PLANE + xbase;

    const float4 z4 = make_float4(0.f, 0.f, 0.f, 0.f);
    float l1 = 0.f;

    if (vx) {
        float4 s_p = z4, s_t = z4, s_pt = z4, s_sq = z4;
        float4 pa = z4, ta = z4, pn = z4, tn = z4, po = z4, to = z4;

        {
            const int g0 = y0 - PAD;
            if (g0 >= 0) {
                pa = *reinterpret_cast<const float4*>(gp + (size_t)g0 * W);
                ta = *reinterpret_cast<const float4*>(gt + (size_t)g0 * W);
            }
            const int g1 = y0 - PAD + 1;
            if (g1 >= 0) {
                pn = *reinterpret_cast<const float4*>(gp + (size_t)g1 * W);
                tn = *reinterpret_cast<const float4*>(gt + (size_t)g1 * W);
            }
        }

        uint2* outp = wsh + (size_t)b * VOL + (size_t)y0 * PLANE + (size_t)z * W + xbase;

#pragma unroll 1
        for (int i = 0; i < NSTEPS; ++i) {
            const float4 p4 = pa, t4 = ta;
            pa = pn; ta = tn;
            {
                const int g = y0 - PAD + i + 2;
                if (i < NSTEPS - 2 && g >= 0 && g < W) {
                    pn = *reinterpret_cast<const float4*>(gp + (size_t)g * W);
                    tn = *reinterpret_cast<const float4*>(gt + (size_t)g * W);
                } else {
                    pn = z4; tn = z4;
                }
            }

            if (i >= PAD && i < PAD + YC) {
                l1 += (fabsf(p4.x - t4.x) + fabsf(p4.y - t4.y)) +
                      (fabsf(p4.z - t4.z) + fabsf(p4.w - t4.w));
            }

            s_p.x += p4.x; s_p.y += p4.y; s_p.z += p4.z; s_p.w += p4.w;
            s_t.x += t4.x; s_t.y += t4.y; s_t.z += t4.z; s_t.w += t4.w;
            s_pt.x += p4.x * t4.x; s_pt.y += p4.y * t4.y;
            s_pt.z += p4.z * t4.z; s_pt.w += p4.w * t4.w;
            s_sq.x += fmaf(p4.x, p4.x, t4.x * t4.x);
            s_sq.y += fmaf(p4.y, p4.y, t4.y * t4.y);
            s_sq.z += fmaf(p4.z, p4.z, t4.z * t4.z);
            s_sq.w += fmaf(p4.w, p4.w, t4.w * t4.w);

            if (i >= WIN) {
                s_p.x -= po.x; s_p.y -= po.y; s_p.z -= po.z; s_p.w -= po.w;
                s_t.x -= to.x; s_t.y -= to.y; s_t.z -= to.z; s_t.w -= to.w;
                s_pt.x -= po.x * to.x; s_pt.y -= po.y * to.y;
                s_pt.z -= po.z * to.z; s_pt.w -= po.w * to.w;
                s_sq.x -= fmaf(po.x, po.x, to.x * to.x);
                s_sq.y -= fmaf(po.y, po.y, to.y * to.y);
                s_sq.z -= fmaf(po.z, po.z, to.z * to.z);
                s_sq.w -= fmaf(po.w, po.w, to.w * to.w);
            }

            if (i >= 2 * PAD) {
                if (i < NSTEPS - 1) {  // prefetch old row for step i+1's subtract
                    const int g = y0 + i - 15;  // (i+1) - 11 - PAD + y0
                    if (g >= 0) {
                        po = *reinterpret_cast<const float4*>(gp + (size_t)g * W);
                        to = *reinterpret_cast<const float4*>(gt + (size_t)g * W);
                    } else {
                        po = z4; to = z4;
                    }
                }
                const float4 w0 = win11x4(s_p);
                const float4 w1 = win11x4(s_t);
                const float4 w2 = win11x4(s_pt);
                const float4 w3 = win11x4(s_sq);
                const uint2 q0 = pack4h(w0.x, w1.x, w2.x, w3.x);
                const uint2 q1 = pack4h(w0.y, w1.y, w2.y, w3.y);
                const uint2 q2 = pack4h(w0.z, w1.z, w2.z, w3.z);
                const uint2 q3 = pack4h(w0.w, w1.w, w2.w, w3.w);
                uint4* o4 = reinterpret_cast<uint4*>(outp);
                o4[0] = make_uint4(q0.x, q0.y, q1.x, q1.y);
                o4[1] = make_uint4(q2.x, q2.y, q3.x, q3.y);
                outp += PLANE;
            }
        }
    }

    l1 += __shfl_xor(l1, 32);
    l1 += __shfl_xor(l1, 16);
    l1 += __shfl_xor(l1, 8);
    l1 += __shfl_xor(l1, 4);
    l1 += __shfl_xor(l1, 2);
    l1 += __shfl_xor(l1, 1);
    if (l == 0) slotW[logical * WPB + wid] = (double)l1;
}

// K3: wide-load ringless z-pass (verified R19 structure). ZCH=12 for 2x
// latency-parallelism. Block = (b, y-pair, z-chunk), 144 threads.
__global__ void k3_zpass(const uint2* __restrict__ wsh, double* __restrict__ slotS) {
    const int t = threadIdx.x;
    int bid = blockIdx.x;
    const int c = bid % ZCH; bid /= ZCH;
    const int yp = bid % (W / 2); bid /= (W / 2);
    const int b = bid;
    const int y = 2 * yp + (t / 72);
    const int xp = t % 72;
    const int zstart = c * ZCL;

    const uint2* F = wsh + (size_t)b * VOL + (size_t)y * PLANE + 2 * xp;

    float a0 = 0.f, a1 = 0.f, a2 = 0.f, a3 = 0.f;
    float b0 = 0.f, b1 = 0.f, b2 = 0.f, b3 = 0.f;
    const float inv = 1.0f / 1331.0f;
    const float C1 = 0.01f * 0.01f;
    const float C2 = 0.03f * 0.03f;
    float ssim_acc = 0.f;

    const int NZ = ZCL + 2 * PAD;  // 22
#pragma unroll 1
    for (int i = 0; i < NZ; ++i) {
        const int zl = zstart - PAD + i;
        if (zl >= 0 && zl < W) {
            const uint4 uu = *reinterpret_cast<const uint4*>(F + (size_t)zl * W);
            const float4 vA = unpack4h(uu.x, uu.y);
            const float4 vB = unpack4h(uu.z, uu.w);
            a0 += vA.x; a1 += vA.y; a2 += vA.z; a3 += vA.w;
            b0 += vB.x; b1 += vB.y; b2 += vB.z; b3 += vB.w;
        }
        const int zo = zl - WIN;
        if (i >= WIN && zo >= 0) {
            const uint4 uu = *reinterpret_cast<const uint4*>(F + (size_t)zo * W);
            const float4 vA = unpack4h(uu.x, uu.y);
            const float4 vB = unpack4h(uu.z, uu.w);
            a0 -= vA.x; a1 -= vA.y; a2 -= vA.z; a3 -= vA.w;
            b0 -= vB.x; b1 -= vB.y; b2 -= vB.z; b3 -= vB.w;
        }
        if (i >= 2 * PAD) {
            {
                const float mu_p = a0 * inv, mu_t = a1 * inv;
                const float ept = a2 * inv, esq = a3 * inv;
                const float mupt = mu_p * mu_t;
                const float musq = mu_p * mu_p + mu_t * mu_t;
                const float num = (2.f * mupt + C1) * (2.f * (ept - mupt) + C2);
                const float den = (musq + C1) * ((esq - musq) + C2);
                ssim_acc += num / den;
            }
            {
                const float mu_p = b0 * inv, mu_t = b1 * inv;
                const float ept = b2 * inv, esq = b3 * inv;
                const float mupt = mu_p * mu_t;
                const float musq = mu_p * mu_p + mu_t * mu_t;
                const float num = (2.f * mupt + C1) * (2.f * (ept - mupt) + C2);
                const float den = (musq + C1) * ((esq - musq) + C2);
                ssim_acc += num / den;
            }
        }
    }

    __shared__ float red[W];
    red[t] = ssim_acc;
    __syncthreads();
    if (t < 16) {
        float s2r = 0.f;
#pragma unroll
        for (int k = 0; k < 9; ++k) s2r += red[t + 16 * k];
        s2r += __shfl_down(s2r, 8);
        s2r += __shfl_down(s2r, 4);
        s2r += __shfl_down(s2r, 2);
        s2r += __shfl_down(s2r, 1);
        if (t == 0) slotS[blockIdx.x] = (double)s2r;
    }
}

// K4: reduce the 2592 + 1728 slots, write the 3 outputs. Deterministic order.
__global__ void k4_final(const double* __restrict__ slotW,
                         const double* __restrict__ slotS, float* __restrict__ out) {
    const int x = threadIdx.x;
    double a = 0.0, s = 0.0;
    for (int i = x; i < NWAVES; i += 256) a += slotW[i];
    for (int i = x; i < NZB; i += 256) s += slotS[i];
    __shared__ double d1[256];
    __shared__ double d2[256];
    d1[x] = a; d2[x] = s;
    __syncthreads();
    for (int st = 128; st > 0; st >>= 1) {
        if (x < st) { d1[x] += d1[x + st]; d2[x] += d2[x + st]; }
        __syncthreads();
    }
    if (x == 0) {
        const double n = (double)NB * (double)VOL;
        const double l1 = d1[0] / n;
        const double ssim_loss = 1.0 - d2[0] / n;
        out[0] = (float)(l1 + 0.5 * ssim_loss);
        out[1] = (float)l1;
        out[2] = (float)ssim_loss;
    }
}

extern "C" void kernel_launch(void* const* d_in, const int* in_sizes, int n_in,
                              void* d_out, int out_size, void* d_ws, size_t ws_size,
                              hipStream_t stream) {
    const float* pred = (const float*)d_in[0];
    const float* targ = (const float*)d_in[1];
    float* out = (float*)d_out;
    uint2* wsh = (uint2*)d_ws;                                  // half4 per voxel, 47.8 MB
    double* slotW = (double*)((char*)d_ws + (size_t)NB * VOL * sizeof(uint2));
    double* slotS = slotW + NWAVES;

    const int nwg = NWAVES / WPB;  // 648 blocks
    kF_xypass<<<nwg, WPB * 64, 0, stream>>>(pred, targ, wsh, slotW);
    k3_zpass<<<NZB, W, 0, stream>>>(wsh, slotS);
    k4_final<<<1, 256, 0, stream>>>(slotW, slotS, out);
}